// Round 6
// baseline (404.855 us; speedup 1.0000x reference)
//
#include <hip/hip_runtime.h>

// Problem constants (from reference setup_inputs)
#define BB 8
#define AA 100000
#define KK 80
#define MM 32
// K1 (anchor kernel) tiling
#define NB1 391             // ceil(AA / 256)
#define NB1_P 392           // padded stride for partials
// K2 (pure neg sweep) tiling
#define K2BLK 256           // blocks per image -> grid (256, 8) = 2048 blocks
#define K2CH  (K2BLK * 256) // 65536 float4 chunk stride per image
#define TOTAL4 (AA * KK / 4)         // 2,000,000 float4 per image
// ALPHA = 0.25, GAMMA = 2.0 baked in below.
//
// r6: SPARSE-CORRECTION SPLIT. r0-r5 established: ~130us for the cls sweep
// across 3 structurally different kernels (occupancy/ILP/atomics/barriers all
// ruled out); VALU-busy ~74us >> ~17us of regular-VALU issue -> the 3
// transcendentals/element (exp, log, rcp) on the slow trans pipe are the
// limiting resource, and per-float4 overhead (codes load, div, ballot,
// branch) breaks pipelining. K2 is now a branch-free pure neg_term sweep;
// positive anchors' k!=ca rows are a sparse exact correction inside K1
// (corr = term2 - term1, ~160k elements total, reuses one trans set).

__device__ __forceinline__ float neg_term(float c) {
    float x   = __builtin_amdgcn_fmed3f(c, 1e-4f, 1.0f - 1e-4f);
    float em  = __expf(-x);
    float u   = 1.0f + em;
    float s   = __logf(u);
    float p   = __builtin_amdgcn_rcpf(u);
    float omp = 1.0f - p;
    return 0.25f * omp * omp * s;
}

// Correction for positive anchor, class k: cls_term(c,ca,k) - neg_term(c).
// Shares one transcendental set; exactly 0.0f for k == ca.
__device__ __forceinline__ float corr_term(float c, int ca, int k) {
    float x   = __builtin_amdgcn_fmed3f(c, 1e-4f, 1.0f - 1e-4f);
    float em  = __expf(-x);
    float u   = 1.0f + em;
    float s   = __logf(u);
    float p   = __builtin_amdgcn_rcpf(u);
    float omp = 1.0f - p;
    float t2  = 0.75f * p * p * (x + s);     // positive, k != ca path
    float t1  = 0.25f * omp * omp * s;       // what K2 already added
    return (k == ca) ? 0.0f : (t2 - t1);
}

// ---- K1: per-anchor IoU/argmax/reg-loss + sparse positive-class correction ----
__global__ __launch_bounds__(256)
void focal_anchors(const float* __restrict__ cls,
                   const float* __restrict__ reg,
                   const float* __restrict__ anc,
                   const float* __restrict__ ann,
                   float* __restrict__ corr_part,  // [BB][NB1_P]
                   float* __restrict__ reg_part_g, // [BB][NB1_P]
                   int*   __restrict__ np_part)    // [BB][NB1_P]
{
    const int blk = blockIdx.x;
    const int b   = blockIdx.y;
    const int t   = threadIdx.x;
    const int a   = blk * 256 + t;
    const bool act = (a < AA);           // last block: t < 160 active

    __shared__ float s_ann[MM * 5];
    __shared__ int   s_wnp[4];
    __shared__ float s_wrg[4];
    __shared__ float s_wcr[4];

    if (t < MM * 5) s_ann[t] = ann[b * MM * 5 + t];
    __syncthreads();

    int   code     = -1;
    float reg_part = 0.0f;
    int   pos      = 0;
    if (act) {
        const float4 av = ((const float4*)anc)[a];
        const float ax1 = av.x, ay1 = av.y, ax2 = av.z, ay2 = av.w;
        float best = -2.0f;           // any real iou (>= -1) beats this
        int   bidx = 0;
        const float a_area = (ax2 - ax1) * (ay2 - ay1);
        #pragma unroll
        for (int m = 0; m < MM; ++m) {
            float bx1 = s_ann[m * 5 + 0], by1 = s_ann[m * 5 + 1];
            float bx2 = s_ann[m * 5 + 2], by2 = s_ann[m * 5 + 3];
            float lab = s_ann[m * 5 + 4];
            float area  = (bx2 - bx1) * (by2 - by1);
            float iw    = fmaxf(fminf(ax2, bx2) - fmaxf(ax1, bx1), 0.0f);
            float ih    = fmaxf(fminf(ay2, by2) - fmaxf(ay1, by1), 0.0f);
            float inter = iw * ih;
            float ua    = fmaxf(a_area + area - inter, 1e-8f);
            float iou   = inter / ua;            // IEEE div: match XLA exactly
            if (lab == -1.0f) iou = -1.0f;
            if (iou > best) { best = iou; bidx = m; }  // strict > = first-argmax
        }
        if (best >= 0.5f) {
            pos  = 1;
            code = (int)s_ann[bidx * 5 + 4];
            float gx1 = s_ann[bidx * 5 + 0], gy1 = s_ann[bidx * 5 + 1];
            float gx2 = s_ann[bidx * 5 + 2], gy2 = s_ann[bidx * 5 + 3];
            float aw  = ax2 - ax1,  ah  = ay2 - ay1;
            float acx = ax1 + 0.5f * aw, acy = ay1 + 0.5f * ah;
            float gw  = gx2 - gx1,  gh  = gy2 - gy1;
            float gcx = gx1 + 0.5f * gw, gcy = gy1 + 0.5f * gh; // before clip!
            gw = fmaxf(gw, 1.0f); gh = fmaxf(gh, 1.0f);
            float tt0 = ((gcx - acx) / aw) / 0.1f;
            float tt1 = ((gcy - acy) / ah) / 0.1f;
            float tt2 = logf(gw / aw) / 0.2f;
            float tt3 = logf(gh / ah) / 0.2f;
            const float4 rv = ((const float4*)reg)[(size_t)b * AA + a];
            float d0 = fabsf(tt0 - rv.x);
            float d1 = fabsf(tt1 - rv.y);
            float d2 = fabsf(tt2 - rv.z);
            float d3 = fabsf(tt3 - rv.w);
            const float th = 1.0f / 9.0f, hb = 0.5f / 9.0f;
            reg_part  = (d0 <= th ? 4.5f * d0 * d0 : d0 - hb)
                      + (d1 <= th ? 4.5f * d1 * d1 : d1 - hb)
                      + (d2 <= th ? 4.5f * d2 * d2 : d2 - hb)
                      + (d3 <= th ? 4.5f * d3 * d3 : d3 - hb);
        }
    }

    // ---- sparse correction: per wave, loop over its positive lanes ----
    // (~1% of anchors; the while body is wave-uniform, lanes sweep classes)
    float corr = 0.0f;
    {
        unsigned long long bal = __ballot(pos != 0);
        const int lane = t & 63;
        const float* __restrict__ crow_base = cls + (size_t)b * ((size_t)AA * KK);
        while (bal) {
            int l = __ffsll((long long)bal) - 1;
            bal &= bal - 1;
            int ca   = __shfl(code, l, 64);            // that lane's class
            int aIdx = (blk * 256 + (t & ~63)) + l;    // its anchor index
            const float* crow = crow_base + (size_t)aIdx * KK;
            float c0 = crow[lane];                     // 256B coalesced
            corr += corr_term(c0, ca, lane);
            if (lane < 16) {
                float c1 = crow[64 + lane];
                corr += corr_term(c1, ca, 64 + lane);
            }
        }
    }

    // wave-level aggregation (no atomics anywhere)
    {
        unsigned long long bal = __ballot(pos != 0);
        int wnp = __popcll(bal);
        float wrg = reg_part, wcr = corr;
        #pragma unroll
        for (int off = 32; off > 0; off >>= 1) {
            wrg += __shfl_down(wrg, off, 64);
            wcr += __shfl_down(wcr, off, 64);
        }
        if ((t & 63) == 0) {
            s_wnp[t >> 6] = wnp; s_wrg[t >> 6] = wrg; s_wcr[t >> 6] = wcr;
        }
    }
    __syncthreads();
    if (t == 0) {
        np_part   [b * NB1_P + blk] = s_wnp[0] + s_wnp[1] + s_wnp[2] + s_wnp[3];
        reg_part_g[b * NB1_P + blk] = s_wrg[0] + s_wrg[1] + s_wrg[2] + s_wrg[3];
        corr_part [b * NB1_P + blk] = s_wcr[0] + s_wcr[1] + s_wcr[2] + s_wcr[3];
    }
}

// ---- K2: branch-free pure neg_term sweep (the 64M-element payload) ----
// No codes, no ballot, no div, no branch: nothing between the loads and the
// trans pipe. Chunks 0..29 are unguarded (max idx 29*65536+65535 < 2e6).
__global__ __launch_bounds__(256, 6)
void focal_neg(const float* __restrict__ cls,
               float* __restrict__ neg_part)       // [BB][K2BLK]
{
    const int b   = blockIdx.y;
    const int t   = threadIdx.x;
    const int gid = blockIdx.x * 256 + t;
    const float4* __restrict__ c4 =
        (const float4*)(cls + (size_t)b * ((size_t)AA * KK));

    float part = 0.0f;

    #pragma unroll 1
    for (int sc = 0; sc < 3; ++sc) {        // 3 superchunks of 10
        const int g0 = gid + sc * 10 * K2CH;
        float4 v[10];
        #pragma unroll
        for (int j = 0; j < 10; ++j) v[j] = c4[g0 + j * K2CH];
        #pragma unroll
        for (int j = 0; j < 10; ++j) {
            part += neg_term(v[j].x);
            part += neg_term(v[j].y);
            part += neg_term(v[j].z);
            part += neg_term(v[j].w);
        }
    }
    {   // chunk 30: partially active (gid < 33920); chunk 31 is empty
        const int g = gid + 30 * K2CH;
        if (g < TOTAL4) {
            float4 v = c4[g];
            part += neg_term(v.x);
            part += neg_term(v.y);
            part += neg_term(v.z);
            part += neg_term(v.w);
        }
    }

    __shared__ float s_wred[4];
    #pragma unroll
    for (int off = 32; off > 0; off >>= 1) part += __shfl_down(part, off, 64);
    if ((t & 63) == 0) s_wred[t >> 6] = part;
    __syncthreads();
    if (t == 0)
        neg_part[b * K2BLK + blockIdx.x] =
            s_wred[0] + s_wred[1] + s_wred[2] + s_wred[3];
}

__global__ __launch_bounds__(256)
void focal_final(const float* __restrict__ ann,
                 const float* __restrict__ neg_part,
                 const float* __restrict__ corr_part,
                 const float* __restrict__ reg_part,
                 const int*   __restrict__ np_part,
                 float* __restrict__ out)
{
    const int t    = threadIdx.x;
    const int lane = t & 63, wid = t >> 6;
    __shared__ double sd[4];
    __shared__ float  sf[4];
    __shared__ int    si[4];
    __shared__ float  s_c[BB], s_r[BB];

    for (int b = 0; b < BB; ++b) {
        double cd = (double)neg_part[b * K2BLK + t];   // exactly 256 slots
        float rf = 0.0f; int np = 0;
        for (int j = t; j < NB1; j += 256) {           // 391 slots
            cd += (double)corr_part[b * NB1_P + j];
            rf += reg_part[b * NB1_P + j];
            np += np_part [b * NB1_P + j];
        }
        #pragma unroll
        for (int off = 32; off > 0; off >>= 1) {
            cd += __shfl_down(cd, off, 64);
            rf += __shfl_down(rf, off, 64);
            np += __shfl_down(np, off, 64);
        }
        if (lane == 0) { sd[wid] = cd; sf[wid] = rf; si[wid] = np; }
        __syncthreads();
        if (t == 0) {
            double cdt = sd[0] + sd[1] + sd[2] + sd[3];
            float  rft = sf[0] + sf[1] + sf[2] + sf[3];
            int    npt = si[0] + si[1] + si[2] + si[3];
            bool has = false;
            for (int m = 0; m < MM; ++m)
                has |= (ann[b * MM * 5 + m * 5 + 4] != -1.0f);
            float npf  = (float)npt;
            float ctot = (float)cdt / fmaxf(npf, 0.01f);
            float rtot = (npt > 0) ? (rft / fmaxf(npf * 4.0f, 1.0f)) : 0.0f;
            s_c[b] = has ? ctot : 0.0f;
            s_r[b] = has ? rtot : 0.0f;
        }
        __syncthreads();   // protects sd/sf/si reuse for next image
    }
    if (t == 0) {
        float c = 0.0f, r = 0.0f;
        for (int b = 0; b < BB; ++b) { c += s_c[b]; r += s_r[b]; }
        out[0] = c / (float)BB;
        out[1] = r / (float)BB;
    }
}

extern "C" void kernel_launch(void* const* d_in, const int* in_sizes, int n_in,
                              void* d_out, int out_size, void* d_ws, size_t ws_size,
                              hipStream_t stream) {
    const float* cls = (const float*)d_in[0];   // (B, A, K)
    const float* reg = (const float*)d_in[1];   // (B, A, 4)
    const float* anc = (const float*)d_in[2];   // (1, A, 4)
    const float* ann = (const float*)d_in[3];   // (B, M, 5)
    float* out = (float*)d_out;                 // [mean_cls, mean_reg]

    // Workspace: every slot written unconditionally before it is read ->
    // no memset, no atomics, poison-robust.
    float* neg_part  = (float*)d_ws;                    // [BB][K2BLK]
    float* corr_part = neg_part + BB * K2BLK;           // [BB][NB1_P]
    float* reg_part  = corr_part + BB * NB1_P;          // [BB][NB1_P]
    int*   np_part   = (int*)(reg_part + BB * NB1_P);   // [BB][NB1_P]

    dim3 g2(K2BLK, BB);               // (256, 8): the big sweep first
    focal_neg<<<g2, 256, 0, stream>>>(cls, neg_part);

    dim3 g1(NB1, BB);                 // (391, 8): anchors + sparse correction
    focal_anchors<<<g1, 256, 0, stream>>>(cls, reg, anc, ann,
                                          corr_part, reg_part, np_part);

    focal_final<<<1, 256, 0, stream>>>(ann, neg_part, corr_part,
                                       reg_part, np_part, out);
}

// Round 7
// 381.739 us; speedup vs baseline: 1.0606x; 1.0606x over previous
//
#include <hip/hip_runtime.h>
#include <cmath>

// Problem constants (from reference setup_inputs)
#define BB 8
#define AA 100000
#define KK 80
#define MM 32
#define APB 391              // anchors per block: 256*391 = 100096 >= 100000
#define NXB 256              // x-blocks per image -> grid (256,8) = 2048 blocks
#define ST4 (NXB * 256)      // 65536: float4 stride between chunks
#define TOTAL4 (AA * KK / 4) // 2,000,000 float4 per image
// ALPHA = 0.25, GAMMA = 2.0 baked in below.
//
// r7: TRANS-ELIMINATION DISCRIMINATOR. r0-r6: four structurally different
// sweeps all pin at ~130us (=320 cyc/wave-elem) with VALU/HBM/occupancy all
// far from ceilings; models for trans-issue and memory both under-predict
// by >3x. This round removes the 3 transcendentals/element from the 64M-elem
// path entirely: degree-12 Chebyshev polynomial (13 FMAs), coefficients
// computed on host in double inside kernel_launch (capture-safe, by-value
// arg), a0 mean-compensated for f32 coefficient rounding. Positive-anchor
// corrections (~160k elems) keep exact trans formulas. Anchors+sweep
// re-fused (r6's split cost ~25us), 8+8 register double-buffer, 2 barriers.

struct FPoly {
    float ih, nmid;      // t = x*ih + nmid maps [lo,hi] -> [-1,1]
    float a[13];         // monomial coeffs in t, Horner order a[12]..a[0]
};

// Exact-trans correction term for positive anchor, class k:
//   cls_term(c,ca,k) - term1(c); exactly 0.0f for k == ca.
__device__ __forceinline__ float corr_term(float c, int ca, int k) {
    float x   = __builtin_amdgcn_fmed3f(c, 1e-4f, 1.0f - 1e-4f);
    float em  = __expf(-x);
    float u   = 1.0f + em;
    float s   = __logf(u);
    float p   = __builtin_amdgcn_rcpf(u);
    float omp = 1.0f - p;
    float t2  = 0.75f * p * p * (x + s);     // positive, k != ca path
    float t1  = 0.25f * omp * omp * s;       // what the sweep already added
    return (k == ca) ? 0.0f : (t2 - t1);
}

// Polynomial negative term: 1 clamp + 1 fma (range map) + 12 fma Horner.
__device__ __forceinline__ float pneg(float c, const FPoly& P) {
    float x  = __builtin_amdgcn_fmed3f(c, 1e-4f, 1.0f - 1e-4f);
    float tt = __builtin_fmaf(x, P.ih, P.nmid);
    float r  = P.a[12];
    #pragma unroll
    for (int k = 11; k >= 0; --k) r = __builtin_fmaf(r, tt, P.a[k]);
    return r;
}

__global__ __launch_bounds__(256, 4)
void focal_main(const float* __restrict__ cls,
                const float* __restrict__ reg,
                const float* __restrict__ anc,
                const float* __restrict__ ann,
                FPoly P,
                float* __restrict__ cls_part,   // [BB][NXB]
                float* __restrict__ reg_part_g, // [BB][NXB]
                int*   __restrict__ np_part)    // [BB][NXB]
{
    const int blk = blockIdx.x, b = blockIdx.y, t = threadIdx.x;
    const int gid = blk * 256 + t;
    const float*  __restrict__ cbase = cls + (size_t)b * ((size_t)AA * KK);
    const float4* __restrict__ c4    = (const float4*)cbase;

    __shared__ float s_ann[MM * 5];
    __shared__ float s_wc[4];
    __shared__ float s_wr[4];
    __shared__ int   s_wn[4];

    if (t < MM * 5) s_ann[t] = ann[b * MM * 5 + t];
    __syncthreads();                 // drains only the ann load (tiny)

    // anchor range owned by this block
    const int a0  = blk * APB;
    const int nAb = min(APB, AA - a0);     // 391, or 295 for blk 255

    // Issue anc loads, then the first sweep batch: all fly under phase B's
    // ~2k cycles of IoU compute. vmcnt retires in order, so anc (issued
    // first) is consumable without draining the batch.
    float4 av0 = make_float4(0.f, 0.f, 0.f, 0.f);
    float4 av1 = make_float4(0.f, 0.f, 0.f, 0.f);
    if (t < nAb)       av0 = ((const float4*)anc)[a0 + t];
    if (256 + t < nAb) av1 = ((const float4*)anc)[a0 + 256 + t];

    float4 vA[8], vB[8];
    #pragma unroll
    for (int j = 0; j < 8; ++j) vA[j] = c4[gid + j * ST4];

    // ---- Phase B: anchors (2 rounds of <=256), exact math, + corrections ----
    int np = 0; float rg = 0.f, corr = 0.f;
    auto do_round = [&](int idx, const float4 av, int roundBase) {
        int   code = -1; float rp = 0.f; int pos = 0;
        if (idx < nAb) {
            const int a = a0 + idx;
            const float ax1 = av.x, ay1 = av.y, ax2 = av.z, ay2 = av.w;
            float best = -2.0f;
            int   bidx = 0;
            const float a_area = (ax2 - ax1) * (ay2 - ay1);
            #pragma unroll
            for (int m = 0; m < MM; ++m) {
                float bx1 = s_ann[m * 5 + 0], by1 = s_ann[m * 5 + 1];
                float bx2 = s_ann[m * 5 + 2], by2 = s_ann[m * 5 + 3];
                float lab = s_ann[m * 5 + 4];
                float area  = (bx2 - bx1) * (by2 - by1);
                float iw    = fmaxf(fminf(ax2, bx2) - fmaxf(ax1, bx1), 0.0f);
                float ih    = fmaxf(fminf(ay2, by2) - fmaxf(ay1, by1), 0.0f);
                float inter = iw * ih;
                float ua    = fmaxf(a_area + area - inter, 1e-8f);
                float iou   = inter / ua;            // IEEE div: match XLA
                if (lab == -1.0f) iou = -1.0f;
                if (iou > best) { best = iou; bidx = m; }  // first-argmax
            }
            if (best >= 0.5f) {
                pos  = 1;
                code = (int)s_ann[bidx * 5 + 4];
                float gx1 = s_ann[bidx * 5 + 0], gy1 = s_ann[bidx * 5 + 1];
                float gx2 = s_ann[bidx * 5 + 2], gy2 = s_ann[bidx * 5 + 3];
                float aw  = ax2 - ax1,  ah  = ay2 - ay1;
                float acx = ax1 + 0.5f * aw, acy = ay1 + 0.5f * ah;
                float gw  = gx2 - gx1,  gh  = gy2 - gy1;
                float gcx = gx1 + 0.5f * gw, gcy = gy1 + 0.5f * gh;
                gw = fmaxf(gw, 1.0f); gh = fmaxf(gh, 1.0f);
                float tt0 = ((gcx - acx) / aw) / 0.1f;
                float tt1 = ((gcy - acy) / ah) / 0.1f;
                float tt2 = logf(gw / aw) / 0.2f;
                float tt3 = logf(gh / ah) / 0.2f;
                const float4 rv = ((const float4*)reg)[(size_t)b * AA + a];
                float d0 = fabsf(tt0 - rv.x);
                float d1 = fabsf(tt1 - rv.y);
                float d2 = fabsf(tt2 - rv.z);
                float d3 = fabsf(tt3 - rv.w);
                const float th = 1.0f / 9.0f, hb = 0.5f / 9.0f;
                rp = (d0 <= th ? 4.5f * d0 * d0 : d0 - hb)
                   + (d1 <= th ? 4.5f * d1 * d1 : d1 - hb)
                   + (d2 <= th ? 4.5f * d2 * d2 : d2 - hb)
                   + (d3 <= th ? 4.5f * d3 * d3 : d3 - hb);
            }
        }
        np += pos; rg += rp;
        // sparse exact correction: wave-serial over its positive lanes
        unsigned long long bal = __ballot(pos != 0);
        const int lane = t & 63;
        while (bal) {
            int l = __ffsll((long long)bal) - 1;
            bal &= bal - 1;
            int ca = __shfl(code, l, 64);
            int aI = a0 + roundBase + (t & ~63) + l;
            const float* crow = cbase + (size_t)aI * KK;
            corr += corr_term(crow[lane], ca, lane);
            if (lane < 16) corr += corr_term(crow[64 + lane], ca, 64 + lane);
        }
    };
    do_round(t,       av0, 0);
    do_round(256 + t, av1, 256);

    // ---- Phase C: pipelined branch-free polynomial sweep (31 chunks) ----
    float part = 0.f;
    auto pneg4 = [&](const float4 v) {
        part += pneg(v.x, P);
        part += pneg(v.y, P);
        part += pneg(v.z, P);
        part += pneg(v.w, P);
    };
    // load B(8..15) first, then consume A(0..7): 8 loads always in flight
    #pragma unroll
    for (int j = 0; j < 8; ++j) vB[j] = c4[gid + (8 + j) * ST4];
    #pragma unroll
    for (int j = 0; j < 8; ++j) pneg4(vA[j]);
    #pragma unroll
    for (int j = 0; j < 8; ++j) vA[j] = c4[gid + (16 + j) * ST4];
    #pragma unroll
    for (int j = 0; j < 8; ++j) pneg4(vB[j]);
    // chunks 24..29 full; 30 guarded (gid < 33920); 31 empty by construction
    #pragma unroll
    for (int j = 0; j < 6; ++j) vB[j] = c4[gid + (24 + j) * ST4];
    const bool last = (gid + 30 * ST4) < TOTAL4;
    vB[6] = make_float4(0.f, 0.f, 0.f, 0.f);
    if (last) vB[6] = c4[gid + 30 * ST4];
    #pragma unroll
    for (int j = 0; j < 8; ++j) pneg4(vA[j]);
    #pragma unroll
    for (int j = 0; j < 6; ++j) pneg4(vB[j]);
    if (last) pneg4(vB[6]);

    // ---- reduce: wave shfl, 4 partials via LDS, one plain store per block ----
    part += corr;
    #pragma unroll
    for (int off = 32; off > 0; off >>= 1) {
        part += __shfl_down(part, off, 64);
        rg   += __shfl_down(rg,   off, 64);
        np   += __shfl_down(np,   off, 64);
    }
    if ((t & 63) == 0) { s_wc[t >> 6] = part; s_wr[t >> 6] = rg; s_wn[t >> 6] = np; }
    __syncthreads();
    if (t == 0) {
        cls_part  [b * NXB + blk] = s_wc[0] + s_wc[1] + s_wc[2] + s_wc[3];
        reg_part_g[b * NXB + blk] = s_wr[0] + s_wr[1] + s_wr[2] + s_wr[3];
        np_part   [b * NXB + blk] = s_wn[0] + s_wn[1] + s_wn[2] + s_wn[3];
    }
}

__global__ __launch_bounds__(256)
void focal_final(const float* __restrict__ ann,
                 const float* __restrict__ cls_part,
                 const float* __restrict__ reg_part,
                 const int*   __restrict__ np_part,
                 float* __restrict__ out)
{
    const int t    = threadIdx.x;
    const int lane = t & 63, wid = t >> 6;
    __shared__ double sd[4];
    __shared__ float  sf[4];
    __shared__ int    si[4];
    __shared__ float  s_c[BB], s_r[BB];

    for (int b = 0; b < BB; ++b) {
        double cd = (double)cls_part[b * NXB + t];   // exactly 256 slots each
        float  rf = reg_part[b * NXB + t];
        int    np = np_part [b * NXB + t];
        #pragma unroll
        for (int off = 32; off > 0; off >>= 1) {
            cd += __shfl_down(cd, off, 64);
            rf += __shfl_down(rf, off, 64);
            np += __shfl_down(np, off, 64);
        }
        if (lane == 0) { sd[wid] = cd; sf[wid] = rf; si[wid] = np; }
        __syncthreads();
        if (t == 0) {
            double cdt = sd[0] + sd[1] + sd[2] + sd[3];
            float  rft = sf[0] + sf[1] + sf[2] + sf[3];
            int    npt = si[0] + si[1] + si[2] + si[3];
            bool has = false;
            for (int m = 0; m < MM; ++m)
                has |= (ann[b * MM * 5 + m * 5 + 4] != -1.0f);
            float npf  = (float)npt;
            float ctot = (float)cdt / fmaxf(npf, 0.01f);
            float rtot = (npt > 0) ? (rft / fmaxf(npf * 4.0f, 1.0f)) : 0.0f;
            s_c[b] = has ? ctot : 0.0f;
            s_r[b] = has ? rtot : 0.0f;
        }
        __syncthreads();   // protects sd/sf/si reuse for next image
    }
    if (t == 0) {
        float c = 0.0f, r = 0.0f;
        for (int b = 0; b < BB; ++b) { c += s_c[b]; r += s_r[b]; }
        out[0] = c / (float)BB;
        out[1] = r / (float)BB;
    }
}

// Host-side: degree-12 Chebyshev interpolant of the negative focal term
//   f(x) = 0.25*(1-p)^2*log(1+e^-x),  p = 1/(1+e^-x),  x in [1e-4, 1-1e-4]
// computed in double; a0 mean-compensated for f32 coefficient rounding so
// the population-mean polynomial error cancels in the 8M-term sum.
static FPoly make_poly() {
    const double PI_D = 3.14159265358979323846;
    const double lo = 1e-4, hi = 1.0 - 1e-4;
    const double mid = 0.5 * (lo + hi), half = 0.5 * (hi - lo);
    const int NC = 13;
    double fv[NC], cheb[NC];
    for (int j = 0; j < NC; ++j) {
        double x  = mid + half * std::cos(PI_D * (j + 0.5) / NC);
        double em = std::exp(-x);
        double u  = 1.0 + em;
        double s  = std::log(u);
        double p  = 1.0 / u;
        double om = 1.0 - p;
        fv[j] = 0.25 * om * om * s;
    }
    for (int k = 0; k < NC; ++k) {
        double acc = 0.0;
        for (int j = 0; j < NC; ++j)
            acc += fv[j] * std::cos(k * PI_D * (j + 0.5) / NC);
        cheb[k] = 2.0 / NC * acc;
    }
    cheb[0] *= 0.5;
    // Chebyshev -> monomial basis in t (double; degree 12 is well-conditioned)
    double mono[NC], Tm2[NC], Tm1[NC], Tc[NC];
    for (int i = 0; i < NC; ++i) { mono[i] = 0.0; Tm2[i] = 0.0; Tm1[i] = 0.0; }
    Tm2[0] = 1.0;   // T0
    Tm1[1] = 1.0;   // T1
    for (int i = 0; i < NC; ++i) mono[i] = cheb[0] * Tm2[i] + cheb[1] * Tm1[i];
    for (int k = 2; k < NC; ++k) {
        for (int i = 0; i < NC; ++i) Tc[i] = -Tm2[i];
        for (int i = NC - 1; i >= 1; --i) Tc[i] += 2.0 * Tm1[i - 1];
        for (int i = 0; i < NC; ++i) mono[i] += cheb[k] * Tc[i];
        for (int i = 0; i < NC; ++i) { Tm2[i] = Tm1[i]; Tm1[i] = Tc[i]; }
    }
    // f32-round a12..a1; fold their mean rounding error into a0
    // (E[t^k] over t~U[-1,1]: 0 for odd k, 1/(k+1) for even k)
    FPoly P;
    double adj = 0.0;
    for (int k = 1; k < NC; ++k) {
        float  fk = (float)mono[k];
        double d  = mono[k] - (double)fk;
        if ((k & 1) == 0) adj += d / (double)(k + 1);
        P.a[k] = fk;
    }
    P.a[0]  = (float)(mono[0] + adj);
    P.ih    = (float)(1.0 / half);
    P.nmid  = (float)(-mid / half);
    return P;
}

extern "C" void kernel_launch(void* const* d_in, const int* in_sizes, int n_in,
                              void* d_out, int out_size, void* d_ws, size_t ws_size,
                              hipStream_t stream) {
    const float* cls = (const float*)d_in[0];   // (B, A, K)
    const float* reg = (const float*)d_in[1];   // (B, A, 4)
    const float* anc = (const float*)d_in[2];   // (1, A, 4)
    const float* ann = (const float*)d_in[3];   // (B, M, 5)
    float* out = (float*)d_out;                 // [mean_cls, mean_reg]

    static const FPoly P = make_poly();         // host double precision, once

    // Workspace: every slot written unconditionally before it is read ->
    // no memset, no atomics, poison-robust.
    float* cls_part = (float*)d_ws;                     // [BB][NXB]
    float* reg_part = cls_part + BB * NXB;              // [BB][NXB]
    int*   np_part  = (int*)(reg_part + BB * NXB);      // [BB][NXB]

    dim3 grid(NXB, BB);                   // (256, 8) = 2048 blocks
    focal_main<<<grid, 256, 0, stream>>>(cls, reg, anc, ann, P,
                                         cls_part, reg_part, np_part);
    focal_final<<<1, 256, 0, stream>>>(ann, cls_part, reg_part, np_part, out);
}

// Round 9
// 377.863 us; speedup vs baseline: 1.0714x; 1.0103x over previous
//
#include <hip/hip_runtime.h>
#include <cmath>

// Problem constants (from reference setup_inputs)
#define BB 8
#define AA 100000
#define KK 80
#define MM 32
#define APB 391              // anchors per block: 256*391 = 100096 >= 100000
#define NXB 256              // x-blocks per image -> grid (256,8) = 2048 blocks
#define ST4 (NXB * 256)      // 65536: float4 stride between chunks
#define TOTAL4 (AA * KK / 4) // 2,000,000 float4 per image
// ALPHA = 0.25, GAMMA = 2.0 baked in below.
//
// r9 = r8 with the nontemporal builtin type fixed (needs a native Clang
// ext-vector, not HIP_vector_type). Experiment unchanged:
// NON-TEMPORAL SWEEP LOADS. r7's poly (zero trans ops in the 64M path)
// was a NULL at ~135us — compute content conclusively exonerated; kernel is
// pinned at 256MB/135us = 1.9 TB/s effective read BW (fillBuffer writes at
// 6.7 on the same box). Theory: the restore leaves cls as dirty/resident
// L3 lines; that read path is the ~2 TB/s limiter. Sweep loads bypass
// cache allocation so cls streams from HBM. Values bit-identical.

typedef float vf4 __attribute__((ext_vector_type(4)));

struct FPoly {
    float ih, nmid;      // t = x*ih + nmid maps [lo,hi] -> [-1,1]
    float a[13];         // monomial coeffs in t, Horner order a[12]..a[0]
};

__device__ __forceinline__ float4 ldnt4(const float4* p) {
    vf4 r = __builtin_nontemporal_load((const vf4*)p);
    return make_float4(r.x, r.y, r.z, r.w);
}

// Exact-trans correction term for positive anchor, class k:
//   cls_term(c,ca,k) - term1(c); exactly 0.0f for k == ca.
__device__ __forceinline__ float corr_term(float c, int ca, int k) {
    float x   = __builtin_amdgcn_fmed3f(c, 1e-4f, 1.0f - 1e-4f);
    float em  = __expf(-x);
    float u   = 1.0f + em;
    float s   = __logf(u);
    float p   = __builtin_amdgcn_rcpf(u);
    float omp = 1.0f - p;
    float t2  = 0.75f * p * p * (x + s);     // positive, k != ca path
    float t1  = 0.25f * omp * omp * s;       // what the sweep already added
    return (k == ca) ? 0.0f : (t2 - t1);
}

// Polynomial negative term: 1 clamp + 1 fma (range map) + 12 fma Horner.
__device__ __forceinline__ float pneg(float c, const FPoly& P) {
    float x  = __builtin_amdgcn_fmed3f(c, 1e-4f, 1.0f - 1e-4f);
    float tt = __builtin_fmaf(x, P.ih, P.nmid);
    float r  = P.a[12];
    #pragma unroll
    for (int k = 11; k >= 0; --k) r = __builtin_fmaf(r, tt, P.a[k]);
    return r;
}

__global__ __launch_bounds__(256, 4)
void focal_main(const float* __restrict__ cls,
                const float* __restrict__ reg,
                const float* __restrict__ anc,
                const float* __restrict__ ann,
                FPoly P,
                float* __restrict__ cls_part,   // [BB][NXB]
                float* __restrict__ reg_part_g, // [BB][NXB]
                int*   __restrict__ np_part)    // [BB][NXB]
{
    const int blk = blockIdx.x, b = blockIdx.y, t = threadIdx.x;
    const int gid = blk * 256 + t;
    const float*  __restrict__ cbase = cls + (size_t)b * ((size_t)AA * KK);
    const float4* __restrict__ c4    = (const float4*)cbase;

    __shared__ float s_ann[MM * 5];
    __shared__ float s_wc[4];
    __shared__ float s_wr[4];
    __shared__ int   s_wn[4];

    if (t < MM * 5) s_ann[t] = ann[b * MM * 5 + t];
    __syncthreads();                 // drains only the ann load (tiny)

    // anchor range owned by this block
    const int a0  = blk * APB;
    const int nAb = min(APB, AA - a0);     // 391, or 295 for blk 255

    // Issue anc loads, then the first sweep batch: all fly under phase B's
    // ~2k cycles of IoU compute. vmcnt retires in order, so anc (issued
    // first) is consumable without draining the batch.
    float4 av0 = make_float4(0.f, 0.f, 0.f, 0.f);
    float4 av1 = make_float4(0.f, 0.f, 0.f, 0.f);
    if (t < nAb)       av0 = ((const float4*)anc)[a0 + t];
    if (256 + t < nAb) av1 = ((const float4*)anc)[a0 + 256 + t];

    float4 vA[8], vB[8];
    #pragma unroll
    for (int j = 0; j < 8; ++j) vA[j] = ldnt4(&c4[gid + j * ST4]);

    // ---- Phase B: anchors (2 rounds of <=256), exact math, + corrections ----
    int np = 0; float rg = 0.f, corr = 0.f;
    auto do_round = [&](int idx, const float4 av, int roundBase) {
        int   code = -1; float rp = 0.f; int pos = 0;
        if (idx < nAb) {
            const int a = a0 + idx;
            const float ax1 = av.x, ay1 = av.y, ax2 = av.z, ay2 = av.w;
            float best = -2.0f;
            int   bidx = 0;
            const float a_area = (ax2 - ax1) * (ay2 - ay1);
            #pragma unroll
            for (int m = 0; m < MM; ++m) {
                float bx1 = s_ann[m * 5 + 0], by1 = s_ann[m * 5 + 1];
                float bx2 = s_ann[m * 5 + 2], by2 = s_ann[m * 5 + 3];
                float lab = s_ann[m * 5 + 4];
                float area  = (bx2 - bx1) * (by2 - by1);
                float iw    = fmaxf(fminf(ax2, bx2) - fmaxf(ax1, bx1), 0.0f);
                float ih    = fmaxf(fminf(ay2, by2) - fmaxf(ay1, by1), 0.0f);
                float inter = iw * ih;
                float ua    = fmaxf(a_area + area - inter, 1e-8f);
                float iou   = inter / ua;            // IEEE div: match XLA
                if (lab == -1.0f) iou = -1.0f;
                if (iou > best) { best = iou; bidx = m; }  // first-argmax
            }
            if (best >= 0.5f) {
                pos  = 1;
                code = (int)s_ann[bidx * 5 + 4];
                float gx1 = s_ann[bidx * 5 + 0], gy1 = s_ann[bidx * 5 + 1];
                float gx2 = s_ann[bidx * 5 + 2], gy2 = s_ann[bidx * 5 + 3];
                float aw  = ax2 - ax1,  ah  = ay2 - ay1;
                float acx = ax1 + 0.5f * aw, acy = ay1 + 0.5f * ah;
                float gw  = gx2 - gx1,  gh  = gy2 - gy1;
                float gcx = gx1 + 0.5f * gw, gcy = gy1 + 0.5f * gh;
                gw = fmaxf(gw, 1.0f); gh = fmaxf(gh, 1.0f);
                float tt0 = ((gcx - acx) / aw) / 0.1f;
                float tt1 = ((gcy - acy) / ah) / 0.1f;
                float tt2 = logf(gw / aw) / 0.2f;
                float tt3 = logf(gh / ah) / 0.2f;
                const float4 rv = ((const float4*)reg)[(size_t)b * AA + a];
                float d0 = fabsf(tt0 - rv.x);
                float d1 = fabsf(tt1 - rv.y);
                float d2 = fabsf(tt2 - rv.z);
                float d3 = fabsf(tt3 - rv.w);
                const float th = 1.0f / 9.0f, hb = 0.5f / 9.0f;
                rp = (d0 <= th ? 4.5f * d0 * d0 : d0 - hb)
                   + (d1 <= th ? 4.5f * d1 * d1 : d1 - hb)
                   + (d2 <= th ? 4.5f * d2 * d2 : d2 - hb)
                   + (d3 <= th ? 4.5f * d3 * d3 : d3 - hb);
            }
        }
        np += pos; rg += rp;
        // sparse exact correction: wave-serial over its positive lanes
        unsigned long long bal = __ballot(pos != 0);
        const int lane = t & 63;
        while (bal) {
            int l = __ffsll((long long)bal) - 1;
            bal &= bal - 1;
            int ca = __shfl(code, l, 64);
            int aI = a0 + roundBase + (t & ~63) + l;
            const float* crow = cbase + (size_t)aI * KK;
            corr += corr_term(crow[lane], ca, lane);
            if (lane < 16) corr += corr_term(crow[64 + lane], ca, 64 + lane);
        }
    };
    do_round(t,       av0, 0);
    do_round(256 + t, av1, 256);

    // ---- Phase C: pipelined branch-free polynomial sweep (31 chunks) ----
    float part = 0.f;
    auto pneg4 = [&](const float4 v) {
        part += pneg(v.x, P);
        part += pneg(v.y, P);
        part += pneg(v.z, P);
        part += pneg(v.w, P);
    };
    // load B(8..15) first, then consume A(0..7): 8 loads always in flight
    #pragma unroll
    for (int j = 0; j < 8; ++j) vB[j] = ldnt4(&c4[gid + (8 + j) * ST4]);
    #pragma unroll
    for (int j = 0; j < 8; ++j) pneg4(vA[j]);
    #pragma unroll
    for (int j = 0; j < 8; ++j) vA[j] = ldnt4(&c4[gid + (16 + j) * ST4]);
    #pragma unroll
    for (int j = 0; j < 8; ++j) pneg4(vB[j]);
    // chunks 24..29 full; 30 guarded (gid < 33920); 31 empty by construction
    #pragma unroll
    for (int j = 0; j < 6; ++j) vB[j] = ldnt4(&c4[gid + (24 + j) * ST4]);
    const bool last = (gid + 30 * ST4) < TOTAL4;
    vB[6] = make_float4(0.f, 0.f, 0.f, 0.f);
    if (last) vB[6] = ldnt4(&c4[gid + 30 * ST4]);
    #pragma unroll
    for (int j = 0; j < 8; ++j) pneg4(vA[j]);
    #pragma unroll
    for (int j = 0; j < 6; ++j) pneg4(vB[j]);
    if (last) pneg4(vB[6]);

    // ---- reduce: wave shfl, 4 partials via LDS, one plain store per block ----
    part += corr;
    #pragma unroll
    for (int off = 32; off > 0; off >>= 1) {
        part += __shfl_down(part, off, 64);
        rg   += __shfl_down(rg,   off, 64);
        np   += __shfl_down(np,   off, 64);
    }
    if ((t & 63) == 0) { s_wc[t >> 6] = part; s_wr[t >> 6] = rg; s_wn[t >> 6] = np; }
    __syncthreads();
    if (t == 0) {
        cls_part  [b * NXB + blk] = s_wc[0] + s_wc[1] + s_wc[2] + s_wc[3];
        reg_part_g[b * NXB + blk] = s_wr[0] + s_wr[1] + s_wr[2] + s_wr[3];
        np_part   [b * NXB + blk] = s_wn[0] + s_wn[1] + s_wn[2] + s_wn[3];
    }
}

__global__ __launch_bounds__(256)
void focal_final(const float* __restrict__ ann,
                 const float* __restrict__ cls_part,
                 const float* __restrict__ reg_part,
                 const int*   __restrict__ np_part,
                 float* __restrict__ out)
{
    const int t    = threadIdx.x;
    const int lane = t & 63, wid = t >> 6;
    __shared__ double sd[4];
    __shared__ float  sf[4];
    __shared__ int    si[4];
    __shared__ float  s_c[BB], s_r[BB];

    for (int b = 0; b < BB; ++b) {
        double cd = (double)cls_part[b * NXB + t];   // exactly 256 slots each
        float  rf = reg_part[b * NXB + t];
        int    np = np_part [b * NXB + t];
        #pragma unroll
        for (int off = 32; off > 0; off >>= 1) {
            cd += __shfl_down(cd, off, 64);
            rf += __shfl_down(rf, off, 64);
            np += __shfl_down(np, off, 64);
        }
        if (lane == 0) { sd[wid] = cd; sf[wid] = rf; si[wid] = np; }
        __syncthreads();
        if (t == 0) {
            double cdt = sd[0] + sd[1] + sd[2] + sd[3];
            float  rft = sf[0] + sf[1] + sf[2] + sf[3];
            int    npt = si[0] + si[1] + si[2] + si[3];
            bool has = false;
            for (int m = 0; m < MM; ++m)
                has |= (ann[b * MM * 5 + m * 5 + 4] != -1.0f);
            float npf  = (float)npt;
            float ctot = (float)cdt / fmaxf(npf, 0.01f);
            float rtot = (npt > 0) ? (rft / fmaxf(npf * 4.0f, 1.0f)) : 0.0f;
            s_c[b] = has ? ctot : 0.0f;
            s_r[b] = has ? rtot : 0.0f;
        }
        __syncthreads();   // protects sd/sf/si reuse for next image
    }
    if (t == 0) {
        float c = 0.0f, r = 0.0f;
        for (int b = 0; b < BB; ++b) { c += s_c[b]; r += s_r[b]; }
        out[0] = c / (float)BB;
        out[1] = r / (float)BB;
    }
}

// Host-side: degree-12 Chebyshev interpolant of the negative focal term
//   f(x) = 0.25*(1-p)^2*log(1+e^-x),  p = 1/(1+e^-x),  x in [1e-4, 1-1e-4]
// computed in double; a0 mean-compensated for f32 coefficient rounding so
// the population-mean polynomial error cancels in the 8M-term sum.
static FPoly make_poly() {
    const double PI_D = 3.14159265358979323846;
    const double lo = 1e-4, hi = 1.0 - 1e-4;
    const double mid = 0.5 * (lo + hi), half = 0.5 * (hi - lo);
    const int NC = 13;
    double fv[NC], cheb[NC];
    for (int j = 0; j < NC; ++j) {
        double x  = mid + half * std::cos(PI_D * (j + 0.5) / NC);
        double em = std::exp(-x);
        double u  = 1.0 + em;
        double s  = std::log(u);
        double p  = 1.0 / u;
        double om = 1.0 - p;
        fv[j] = 0.25 * om * om * s;
    }
    for (int k = 0; k < NC; ++k) {
        double acc = 0.0;
        for (int j = 0; j < NC; ++j)
            acc += fv[j] * std::cos(k * PI_D * (j + 0.5) / NC);
        cheb[k] = 2.0 / NC * acc;
    }
    cheb[0] *= 0.5;
    // Chebyshev -> monomial basis in t (double; degree 12 is well-conditioned)
    double mono[NC], Tm2[NC], Tm1[NC], Tc[NC];
    for (int i = 0; i < NC; ++i) { mono[i] = 0.0; Tm2[i] = 0.0; Tm1[i] = 0.0; }
    Tm2[0] = 1.0;   // T0
    Tm1[1] = 1.0;   // T1
    for (int i = 0; i < NC; ++i) mono[i] = cheb[0] * Tm2[i] + cheb[1] * Tm1[i];
    for (int k = 2; k < NC; ++k) {
        for (int i = 0; i < NC; ++i) Tc[i] = -Tm2[i];
        for (int i = NC - 1; i >= 1; --i) Tc[i] += 2.0 * Tm1[i - 1];
        for (int i = 0; i < NC; ++i) mono[i] += cheb[k] * Tc[i];
        for (int i = 0; i < NC; ++i) { Tm2[i] = Tm1[i]; Tm1[i] = Tc[i]; }
    }
    // f32-round a12..a1; fold their mean rounding error into a0
    // (E[t^k] over t~U[-1,1]: 0 for odd k, 1/(k+1) for even k)
    FPoly P;
    double adj = 0.0;
    for (int k = 1; k < NC; ++k) {
        float  fk = (float)mono[k];
        double d  = mono[k] - (double)fk;
        if ((k & 1) == 0) adj += d / (double)(k + 1);
        P.a[k] = fk;
    }
    P.a[0]  = (float)(mono[0] + adj);
    P.ih    = (float)(1.0 / half);
    P.nmid  = (float)(-mid / half);
    return P;
}

extern "C" void kernel_launch(void* const* d_in, const int* in_sizes, int n_in,
                              void* d_out, int out_size, void* d_ws, size_t ws_size,
                              hipStream_t stream) {
    const float* cls = (const float*)d_in[0];   // (B, A, K)
    const float* reg = (const float*)d_in[1];   // (B, A, 4)
    const float* anc = (const float*)d_in[2];   // (1, A, 4)
    const float* ann = (const float*)d_in[3];   // (B, M, 5)
    float* out = (float*)d_out;                 // [mean_cls, mean_reg]

    static const FPoly P = make_poly();         // host double precision, once

    // Workspace: every slot written unconditionally before it is read ->
    // no memset, no atomics, poison-robust.
    float* cls_part = (float*)d_ws;                     // [BB][NXB]
    float* reg_part = cls_part + BB * NXB;              // [BB][NXB]
    int*   np_part  = (int*)(reg_part + BB * NXB);      // [BB][NXB]

    dim3 grid(NXB, BB);                   // (256, 8) = 2048 blocks
    focal_main<<<grid, 256, 0, stream>>>(cls, reg, anc, ann, P,
                                         cls_part, reg_part, np_part);
    focal_final<<<1, 256, 0, stream>>>(ann, cls_part, reg_part, np_part, out);
}